// Round 3
// baseline (4130.629 us; speedup 1.0000x reference)
//
#include <hip/hip_runtime.h>
#include <cstdint>
#include <cstddef>

// Problem constants
#define NB 4096
#define NL 50
#define NT 64
#define NF 3
#define NH 20
#define NO 16
#define NN (NB*NL)   // 204800 sequences
#define NW (NN/64)   // 3200 waves

// LSTM x-tile staging
#define TS 8                 // steps per tile
#define TF3 (TS*NF)          // 24 floats per sequence per tile
#define LSTR 28              // LDS stride (floats): 112B per seq -> 16B-aligned b128 writes

// ---------------- fast transcendentals (v_exp_f32 + v_rcp_f32) ----------------
__device__ __forceinline__ float fsig(float z) {
    return __builtin_amdgcn_rcpf(1.0f + __expf(-z));
}
__device__ __forceinline__ float ftanh(float z) {
    return 1.0f - 2.0f * __builtin_amdgcn_rcpf(1.0f + __expf(2.0f * z));
}

// ---------------- counting sort by length (64 buckets) ----------------
__global__ __launch_bounds__(256) void hist_kernel(const int* __restrict__ lengths,
                                                   int* __restrict__ hist) {
    __shared__ int lh[64];
    int tid = threadIdx.x;
    if (tid < 64) lh[tid] = 0;
    __syncthreads();
    int n = blockIdx.x * 256 + tid;
    if (n < NN) {
        int len = lengths[n];
        len = len < 0 ? 0 : (len > 63 ? 63 : len);
        atomicAdd(&lh[len], 1);
    }
    __syncthreads();
    if (tid < 64 && lh[tid] != 0) atomicAdd(&hist[tid], lh[tid]);
}

// 64-lane shfl exclusive scan
__global__ void scan_kernel(const int* __restrict__ hist, int* __restrict__ cursor) {
    int l = threadIdx.x;          // 0..63
    int v = hist[l];
    int s = v;
#pragma unroll
    for (int d = 1; d < 64; d <<= 1) {
        int o = __shfl_up(s, d);
        if (l >= d) s += o;
    }
    cursor[l] = s - v;            // exclusive prefix
}

__global__ __launch_bounds__(256) void scatter_kernel(const int* __restrict__ lengths,
                                                      int* __restrict__ cursor,
                                                      int* __restrict__ order,
                                                      int* __restrict__ len_s) {
    __shared__ int lcnt[64];
    __shared__ int lbase[64];
    int tid = threadIdx.x;
    if (tid < 64) lcnt[tid] = 0;
    __syncthreads();
    int n = blockIdx.x * 256 + tid;
    int len = 0, myrank = 0;
    if (n < NN) {
        len = lengths[n];
        len = len < 0 ? 0 : (len > 63 ? 63 : len);
        myrank = atomicAdd(&lcnt[len], 1);
    }
    __syncthreads();
    if (tid < 64 && lcnt[tid] != 0) lbase[tid] = atomicAdd(&cursor[tid], lcnt[tid]);
    __syncthreads();
    if (n < NN) {
        int pos = lbase[len] + myrank;
        order[pos] = n;
        len_s[pos] = len;
    }
}

// ---------------- bias precompute: bsum = b_ih + b_hh ----------------
__global__ void bias_kernel(const float* __restrict__ b_ih,
                            const float* __restrict__ b_hh,
                            float* __restrict__ bsum) {
    int t = threadIdx.x;
    if (t < 80) bsum[t] = b_ih[t] + b_hh[t];
}

// ---------------- LSTM + summary linear ----------------
// One wave per block; one sequence per lane (sorted by length).
// x tiles (8 steps x 3 feats x 64 seqs) staged through LDS via coalesced
// per-sequence float4 gathers, software-pipelined one tile ahead.
__global__ __launch_bounds__(64) void lstm_kernel(
    const float* __restrict__ x,        // [NN][64][3]
    const int*   __restrict__ len_s,    // [NN] sorted lengths
    const int*   __restrict__ order,    // [NN] sorted-by-length indices
    const float* __restrict__ w_ih,     // [80][3]
    const float* __restrict__ w_hh,     // [80][20]
    const float* __restrict__ bsum,     // [80]
    const float* __restrict__ w_lin,    // [16][20]
    const float* __restrict__ b_lin,    // [16]
    float* __restrict__ feat)           // [NN][16]
{
    __shared__ float xt[64 * LSTR];     // 7 KB, wave-private

    const int lane = threadIdx.x;
    const int w    = blockIdx.x;
    const int i    = (w << 6) | lane;
    const int mylen = len_s[i];
    const int n     = order[i];
    const int wavemax = __shfl(mylen, 63);   // ascending sort: lane 63 holds max

    float h[NH], c[NH];
#pragma unroll
    for (int u = 0; u < NH; ++u) { h[u] = 0.0f; c[u] = 0.0f; }

    if (wavemax > 0) {
        // Static gather map: 384 float4s per tile = 64 seqs x 6 chunks; lane j-th
        // element e4 = lane + 64*j -> (s = e4/6, q = e4%6). Loop-invariant.
        size_t gbase[6];
        int    laddr[6];
#pragma unroll
        for (int j = 0; j < 6; ++j) {
            int e4 = lane + 64 * j;
            int s  = e4 / 6;
            int q  = e4 - 6 * s;
            int ns = __shfl(n, s);                 // seq id owned by lane s
            gbase[j] = (size_t)ns * (NT * NF) + q * 4;
            laddr[j] = s * LSTR + q * 4;
        }

        float4 v[6];
        // prologue: load tile 0
#pragma unroll
        for (int j = 0; j < 6; ++j)
            v[j] = *(const float4*)(x + gbase[j]);

        for (int t0 = 0; t0 < wavemax; t0 += TS) {
            __syncthreads();                       // single-wave block: cheap
#pragma unroll
            for (int j = 0; j < 6; ++j)
                *(float4*)&xt[laddr[j]] = v[j];
            __syncthreads();

            // prefetch next tile while computing this one
            if (t0 + TS < wavemax) {
                size_t off = (size_t)(t0 + TS) * NF;
#pragma unroll
                for (int j = 0; j < 6; ++j)
                    v[j] = *(const float4*)(x + gbase[j] + off);
            }

            const float* xl = &xt[lane * LSTR];
            int kmax = wavemax - t0; if (kmax > TS) kmax = TS;
            for (int k = 0; k < kmax; ++k) {
                float x0 = xl[k * 3 + 0];
                float x1 = xl[k * 3 + 1];
                float x2 = xl[k * 3 + 2];
                bool m = (t0 + k) < mylen;
                float hn[NH];
#pragma unroll
                for (int u = 0; u < NH; ++u) {
                    float z[4];
#pragma unroll
                    for (int g = 0; g < 4; ++g) {
                        int r = g * NH + u;        // torch gate order i,f,g,o
                        float a = bsum[r];
                        a += w_ih[r * 3 + 0] * x0;
                        a += w_ih[r * 3 + 1] * x1;
                        a += w_ih[r * 3 + 2] * x2;
#pragma unroll
                        for (int kk = 0; kk < NH; ++kk) a += w_hh[r * NH + kk] * h[kk];
                        z[g] = a;
                    }
                    float ig = fsig(z[0]);
                    float fg = fsig(z[1]);
                    float gg = ftanh(z[2]);
                    float og = fsig(z[3]);
                    float cn = fg * c[u] + ig * gg;
                    float hv = og * ftanh(cn);
                    c[u]  = m ? cn : c[u];
                    hn[u] = m ? hv : h[u];
                }
#pragma unroll
                for (int u = 0; u < NH; ++u) h[u] = hn[u];
            }
        }
    }

    float* fp = feat + (size_t)n * NO;
    if (mylen > 0) {
#pragma unroll
        for (int o = 0; o < NO; ++o) {
            float a = b_lin[o];
#pragma unroll
            for (int k = 0; k < NH; ++k) a += w_lin[o * NH + k] * h[k];
            fp[o] = fsig(a);
        }
    } else {
#pragma unroll
        for (int o = 0; o < NO; ++o) fp[o] = 0.0f;
    }
}

// ---------------- conv stack + fc head (one wave per batch row) ----------------
__global__ __launch_bounds__(64) void head_kernel(
    const float* __restrict__ feat,  // [NB][NL][16]
    const float* __restrict__ c1w, const float* __restrict__ c1b,   // [32][16][5], [32]
    const float* __restrict__ c2w, const float* __restrict__ c2b,   // [32][32][4], [32]
    const float* __restrict__ c3w, const float* __restrict__ c3b,   // [32][32][4], [32]
    const float* __restrict__ f1w, const float* __restrict__ f1b,   // [16][608], [16]
    const float* __restrict__ f2w, const float* __restrict__ f2b,   // [4][16], [4]
    float* __restrict__ out)         // [NB][4]
{
    const int b   = blockIdx.x;
    const int tid = threadIdx.x;

    __shared__ float sf[16 * 50];   // [ch][pos]
    __shared__ float y1[32 * 46];
    __shared__ float y2[32 * 22];
    __shared__ float y3[32 * 19];
    __shared__ float r1[16];

    const float* fb = feat + (size_t)b * (NL * NO);
    for (int i = tid; i < NL * NO; i += 64) {
        int l = i >> 4, o = i & 15;
        sf[o * 50 + l] = fb[i];
    }
    __syncthreads();

    // conv1: 16ch k5 s1 -> 32ch x 46, relu
    if (tid < 46) {
        float acc[32];
#pragma unroll
        for (int oc = 0; oc < 32; ++oc) acc[oc] = c1b[oc];
#pragma unroll
        for (int ic = 0; ic < 16; ++ic) {
#pragma unroll
            for (int tap = 0; tap < 5; ++tap) {
                float fv = sf[ic * 50 + tid + tap];
#pragma unroll
                for (int oc = 0; oc < 32; ++oc)
                    acc[oc] += c1w[(oc * 16 + ic) * 5 + tap] * fv;
            }
        }
#pragma unroll
        for (int oc = 0; oc < 32; ++oc) y1[oc * 46 + tid] = fmaxf(acc[oc], 0.0f);
    }
    __syncthreads();

    // conv2: 32ch k4 s2 -> 32ch x 22, relu  (2 oc-halves x 22 pos)
    {
        int half = tid >> 5;
        int pos  = tid & 31;
        if (pos < 22) {
            int oc0 = half * 16;
            float acc[16];
#pragma unroll
            for (int oc = 0; oc < 16; ++oc) acc[oc] = c2b[oc0 + oc];
#pragma unroll
            for (int ic = 0; ic < 32; ++ic) {
#pragma unroll
                for (int tap = 0; tap < 4; ++tap) {
                    float fv = y1[ic * 46 + 2 * pos + tap];
#pragma unroll
                    for (int oc = 0; oc < 16; ++oc)
                        acc[oc] += c2w[((oc0 + oc) * 32 + ic) * 4 + tap] * fv;
                }
            }
#pragma unroll
            for (int oc = 0; oc < 16; ++oc) y2[(oc0 + oc) * 22 + pos] = fmaxf(acc[oc], 0.0f);
        }
    }
    __syncthreads();

    // conv3: 32ch k4 s1 -> 32ch x 19, relu  (2 oc-halves x 19 pos)
    {
        int half = tid >> 5;
        int pos  = tid & 31;
        if (pos < 19) {
            int oc0 = half * 16;
            float acc[16];
#pragma unroll
            for (int oc = 0; oc < 16; ++oc) acc[oc] = c3b[oc0 + oc];
#pragma unroll
            for (int ic = 0; ic < 32; ++ic) {
#pragma unroll
                for (int tap = 0; tap < 4; ++tap) {
                    float fv = y2[ic * 22 + pos + tap];
#pragma unroll
                    for (int oc = 0; oc < 16; ++oc)
                        acc[oc] += c3w[((oc0 + oc) * 32 + ic) * 4 + tap] * fv;
                }
            }
#pragma unroll
            for (int oc = 0; oc < 16; ++oc) y3[(oc0 + oc) * 19 + pos] = fmaxf(acc[oc], 0.0f);
        }
    }
    __syncthreads();

    // fc1: 608 -> 16, relu. lane = (u, quarter); 152 k's per lane; shfl reduce.
    {
        int u = tid & 15;
        int q = tid >> 4;          // 0..3
        float acc = 0.0f;
        int k0 = q * 152;
#pragma unroll 8
        for (int k = k0; k < k0 + 152; ++k) acc += f1w[u * 608 + k] * y3[k];
        acc += __shfl_xor(acc, 16);
        acc += __shfl_xor(acc, 32);
        if (tid < 16) r1[tid] = fmaxf(acc + f1b[tid], 0.0f);
    }
    __syncthreads();

    // fc2: 16 -> 4
    if (tid < 4) {
        float s = f2b[tid];
#pragma unroll
        for (int k = 0; k < 16; ++k) s += f2w[tid * 16 + k] * r1[k];
        out[(size_t)b * 4 + tid] = s;
    }
}

extern "C" void kernel_launch(void* const* d_in, const int* in_sizes, int n_in,
                              void* d_out, int out_size, void* d_ws, size_t ws_size,
                              hipStream_t stream)
{
    const float* x     = (const float*)d_in[0];
    const int*  lengths= (const int*)  d_in[1];
    const float* w_ih  = (const float*)d_in[2];
    const float* w_hh  = (const float*)d_in[3];
    const float* b_ih  = (const float*)d_in[4];
    const float* b_hh  = (const float*)d_in[5];
    const float* w_lin = (const float*)d_in[6];
    const float* b_lin = (const float*)d_in[7];
    const float* c1w   = (const float*)d_in[8];
    const float* c1b   = (const float*)d_in[9];
    const float* c2w   = (const float*)d_in[10];
    const float* c2b   = (const float*)d_in[11];
    const float* c3w   = (const float*)d_in[12];
    const float* c3b   = (const float*)d_in[13];
    const float* f1w   = (const float*)d_in[14];
    const float* f1b   = (const float*)d_in[15];
    const float* f2w   = (const float*)d_in[16];
    const float* f2b   = (const float*)d_in[17];
    float* out = (float*)d_out;

    // workspace layout (~15 MB total)
    char* ws      = (char*)d_ws;
    float* feat   = (float*)ws;                       // NN*16 floats
    int*   order  = (int*)(feat + (size_t)NN * NO);   // NN
    int*   len_s  = order + NN;                       // NN
    int*   hist   = len_s + NN;                       // 64
    int*   cursor = hist + 64;                        // 64
    float* bsum   = (float*)(cursor + 64);            // 80

    hipMemsetAsync(hist, 0, 64 * sizeof(int), stream);
    hist_kernel   <<<NN / 256, 256, 0, stream>>>(lengths, hist);
    scan_kernel   <<<1, 64, 0, stream>>>(hist, cursor);
    scatter_kernel<<<NN / 256, 256, 0, stream>>>(lengths, cursor, order, len_s);
    bias_kernel   <<<1, 128, 0, stream>>>(b_ih, b_hh, bsum);
    lstm_kernel   <<<NW, 64, 0, stream>>>(x, len_s, order, w_ih, w_hh, bsum,
                                          w_lin, b_lin, feat);
    head_kernel   <<<NB, 64, 0, stream>>>(feat, c1w, c1b, c2w, c2b, c3w, c3b,
                                          f1w, f1b, f2w, f2b, out);
}

// Round 4
// 1499.174 us; speedup vs baseline: 2.7553x; 2.7553x over previous
//
#include <hip/hip_runtime.h>
#include <cstdint>
#include <cstddef>

// Problem constants
#define NB 4096
#define NL 50
#define NT 64
#define NF 3
#define NH 20
#define NO 16
#define NN (NB*NL)   // 204800 sequences

// LSTM kernel geometry: 256-thread block = 64 seqs x 4 gate-waves
#define TS 16        // steps per x tile
#define XTS 52       // xt LDS stride (dwords): 48 data + 4 pad, 208B = 16B-aligned
#define ZS 81        // z LDS stride (odd -> <=2-way conflicts)
#define HS 21        // h LDS stride (odd -> 2-way, free)

// ---------------- fast transcendentals (v_exp_f32 + v_rcp_f32) ----------------
__device__ __forceinline__ float fsig(float z) {
    return __builtin_amdgcn_rcpf(1.0f + __expf(-z));
}
__device__ __forceinline__ float ftanh(float z) {
    return 1.0f - 2.0f * __builtin_amdgcn_rcpf(1.0f + __expf(2.0f * z));
}

// ---------------- counting sort by length (64 buckets) ----------------
__global__ __launch_bounds__(256) void hist_kernel(const int* __restrict__ lengths,
                                                   int* __restrict__ hist) {
    __shared__ int lh[64];
    int tid = threadIdx.x;
    if (tid < 64) lh[tid] = 0;
    __syncthreads();
    int n = blockIdx.x * 256 + tid;
    if (n < NN) {
        int len = lengths[n];
        len = len < 0 ? 0 : (len > 63 ? 63 : len);
        atomicAdd(&lh[len], 1);
    }
    __syncthreads();
    if (tid < 64 && lh[tid] != 0) atomicAdd(&hist[tid], lh[tid]);
}

// 64-lane shfl exclusive scan
__global__ void scan_kernel(const int* __restrict__ hist, int* __restrict__ cursor) {
    int l = threadIdx.x;          // 0..63
    int v = hist[l];
    int s = v;
#pragma unroll
    for (int d = 1; d < 64; d <<= 1) {
        int o = __shfl_up(s, d);
        if (l >= d) s += o;
    }
    cursor[l] = s - v;            // exclusive prefix
}

__global__ __launch_bounds__(256) void scatter_kernel(const int* __restrict__ lengths,
                                                      int* __restrict__ cursor,
                                                      int* __restrict__ order,
                                                      int* __restrict__ len_s) {
    __shared__ int lcnt[64];
    __shared__ int lbase[64];
    int tid = threadIdx.x;
    if (tid < 64) lcnt[tid] = 0;
    __syncthreads();
    int n = blockIdx.x * 256 + tid;
    int len = 0, myrank = 0;
    if (n < NN) {
        len = lengths[n];
        len = len < 0 ? 0 : (len > 63 ? 63 : len);
        myrank = atomicAdd(&lcnt[len], 1);
    }
    __syncthreads();
    if (tid < 64 && lcnt[tid] != 0) lbase[tid] = atomicAdd(&cursor[tid], lcnt[tid]);
    __syncthreads();
    if (n < NN) {
        int pos = lbase[len] + myrank;
        order[pos] = n;
        len_s[pos] = len;
    }
}

// ---------------- bias precompute: bsum = b_ih + b_hh ----------------
__global__ void bias_kernel(const float* __restrict__ b_ih,
                            const float* __restrict__ b_hh,
                            float* __restrict__ bsum) {
    int t = threadIdx.x;
    if (t < 80) bsum[t] = b_ih[t] + b_hh[t];
}

// ---------------- LSTM + summary linear ----------------
// Block = 64 sequences (sorted by length) x 4 waves. Wave V computes gate-type V
// (i,f,g,o) for all 64 seqs: lane s handles seq s, 20 units. Gate index is
// wave-uniform (readfirstlane) so weights ride the s_load/SGPR path. h and
// activated gates exchanged via LDS; per-thread persistent state is c[5] only
// (no spills). x staged in 16-step coalesced float4 tiles, pipelined.
__global__ __launch_bounds__(256) void lstm_kernel(
    const float* __restrict__ x,        // [NN][64][3]
    const int*   __restrict__ len_s,    // [NN] sorted lengths
    const int*   __restrict__ order,    // [NN] sorted-by-length indices
    const float* __restrict__ w_ih,     // [80][3]
    const float* __restrict__ w_hh,     // [80][20]
    const float* __restrict__ bsum,     // [80]
    const float* __restrict__ w_lin,    // [16][20]
    const float* __restrict__ b_lin,    // [16]
    float* __restrict__ feat)           // [NN][16]
{
    __shared__ float xt[64 * XTS];      // 13.0 KB
    __shared__ float zb[64 * ZS];       // 20.3 KB (activated gates)
    __shared__ float hb[64 * HS];       //  5.3 KB (hidden state)

    const int tid  = threadIdx.x;
    const int blk  = blockIdx.x;
    const int s    = tid & 63;                                   // seq within block
    const int V    = __builtin_amdgcn_readfirstlane(tid >> 6);   // gate type 0..3
    const int base = blk * 64;

    const int mylen    = len_s[base + s];
    const int blockmax = len_s[base + 63];    // ascending sort

    // zero-init hidden state
    for (int i2 = tid; i2 < 64 * HS; i2 += 256) hb[i2] = 0.0f;

    // x gather map: 64 seqs x 12 float4 per tile = 768 float4 = 3/thread
    size_t gb[3]; int la[3];
#pragma unroll
    for (int j = 0; j < 3; ++j) {
        int e4 = tid + 256 * j;
        int ss = e4 / 12;
        int q  = e4 - 12 * ss;
        int ns = order[base + ss];
        gb[j] = (size_t)ns * (NT * NF) + q * 4;
        la[j] = ss * XTS + q * 4;
    }

    float c5[5];
#pragma unroll
    for (int j = 0; j < 5; ++j) c5[j] = 0.0f;

    __syncthreads();    // hb init visible

    if (blockmax > 0) {
        float4 vf[3];
#pragma unroll
        for (int j = 0; j < 3; ++j) vf[j] = *(const float4*)(x + gb[j]);

        for (int t0 = 0; t0 < blockmax; t0 += TS) {
#pragma unroll
            for (int j = 0; j < 3; ++j) *(float4*)&xt[la[j]] = vf[j];
            __syncthreads();

            // prefetch next tile while computing this one
            if (t0 + TS < blockmax) {
                size_t off = (size_t)(t0 + TS) * NF;
#pragma unroll
                for (int j = 0; j < 3; ++j)
                    vf[j] = *(const float4*)(x + gb[j] + off);
            }

            int kmax = blockmax - t0; if (kmax > TS) kmax = TS;
            for (int k = 0; k < kmax; ++k) {
                // ---- phase 1: wave V computes activated gate-V values for seq s
                float hv[20];
#pragma unroll
                for (int kk = 0; kk < 20; ++kk) hv[kk] = hb[s * HS + kk];
                float x0 = xt[s * XTS + k * 3 + 0];
                float x1 = xt[s * XTS + k * 3 + 1];
                float x2 = xt[s * XTS + k * 3 + 2];
#pragma unroll
                for (int u = 0; u < 20; ++u) {
                    int r = V * 20 + u;            // wave-uniform row
                    float a = bsum[r];
                    a += w_ih[r * 3 + 0] * x0;
                    a += w_ih[r * 3 + 1] * x1;
                    a += w_ih[r * 3 + 2] * x2;
#pragma unroll
                    for (int kk = 0; kk < 20; ++kk) a += w_hh[r * 20 + kk] * hv[kk];
                    a = (V == 2) ? ftanh(a) : fsig(a);   // wave-uniform branch
                    zb[s * ZS + V * 20 + u] = a;
                }
                __syncthreads();

                // ---- phase 2: wave V updates units u = 5V..5V+4 of seq s
                bool m = (t0 + k) < mylen;
#pragma unroll
                for (int j = 0; j < 5; ++j) {
                    int u = 5 * V + j;
                    float zi = zb[s * ZS +      u];
                    float zf = zb[s * ZS + 20 + u];
                    float zg = zb[s * ZS + 40 + u];
                    float zo = zb[s * ZS + 60 + u];
                    float ho = hb[s * HS + u];       // only this thread touches it
                    float cn = zf * c5[j] + zi * zg;
                    float hn = zo * ftanh(cn);
                    if (m) c5[j] = cn;
                    hb[s * HS + u] = m ? hn : ho;
                }
                __syncthreads();
            }
        }
    }

    // ---- epilogue: summary linear. Thread (s,V) -> outputs o = 4V..4V+3
    int n = order[base + s];
    float4 res;
    if (mylen > 0) {
        float r4[4];
#pragma unroll
        for (int j = 0; j < 4; ++j) {
            int o = 4 * V + j;                     // wave-uniform row
            float a = b_lin[o];
#pragma unroll
            for (int kk = 0; kk < 20; ++kk) a += w_lin[o * 20 + kk] * hb[s * HS + kk];
            r4[j] = fsig(a);
        }
        res = make_float4(r4[0], r4[1], r4[2], r4[3]);
    } else {
        res = make_float4(0.f, 0.f, 0.f, 0.f);
    }
    *(float4*)(feat + (size_t)n * NO + 4 * V) = res;
}

// ---------------- conv stack + fc head (one wave per batch row) ----------------
__global__ __launch_bounds__(64) void head_kernel(
    const float* __restrict__ feat,  // [NB][NL][16]
    const float* __restrict__ c1w, const float* __restrict__ c1b,   // [32][16][5], [32]
    const float* __restrict__ c2w, const float* __restrict__ c2b,   // [32][32][4], [32]
    const float* __restrict__ c3w, const float* __restrict__ c3b,   // [32][32][4], [32]
    const float* __restrict__ f1w, const float* __restrict__ f1b,   // [16][608], [16]
    const float* __restrict__ f2w, const float* __restrict__ f2b,   // [4][16], [4]
    float* __restrict__ out)         // [NB][4]
{
    const int b   = blockIdx.x;
    const int tid = threadIdx.x;

    __shared__ float sf[16 * 50];   // [ch][pos]
    __shared__ float y1[32 * 46];
    __shared__ float y2[32 * 22];
    __shared__ float y3[32 * 19];
    __shared__ float r1[16];

    const float* fb = feat + (size_t)b * (NL * NO);
    for (int i = tid; i < NL * NO; i += 64) {
        int l = i >> 4, o = i & 15;
        sf[o * 50 + l] = fb[i];
    }
    __syncthreads();

    // conv1: 16ch k5 s1 -> 32ch x 46, relu
    if (tid < 46) {
        float acc[32];
#pragma unroll
        for (int oc = 0; oc < 32; ++oc) acc[oc] = c1b[oc];
#pragma unroll
        for (int ic = 0; ic < 16; ++ic) {
#pragma unroll
            for (int tap = 0; tap < 5; ++tap) {
                float fv = sf[ic * 50 + tid + tap];
#pragma unroll
                for (int oc = 0; oc < 32; ++oc)
                    acc[oc] += c1w[(oc * 16 + ic) * 5 + tap] * fv;
            }
        }
#pragma unroll
        for (int oc = 0; oc < 32; ++oc) y1[oc * 46 + tid] = fmaxf(acc[oc], 0.0f);
    }
    __syncthreads();

    // conv2: 32ch k4 s2 -> 32ch x 22, relu  (2 oc-halves x 22 pos)
    {
        int half = tid >> 5;
        int pos  = tid & 31;
        if (pos < 22) {
            int oc0 = half * 16;
            float acc[16];
#pragma unroll
            for (int oc = 0; oc < 16; ++oc) acc[oc] = c2b[oc0 + oc];
#pragma unroll
            for (int ic = 0; ic < 32; ++ic) {
#pragma unroll
                for (int tap = 0; tap < 4; ++tap) {
                    float fv = y1[ic * 46 + 2 * pos + tap];
#pragma unroll
                    for (int oc = 0; oc < 16; ++oc)
                        acc[oc] += c2w[((oc0 + oc) * 32 + ic) * 4 + tap] * fv;
                }
            }
#pragma unroll
            for (int oc = 0; oc < 16; ++oc) y2[(oc0 + oc) * 22 + pos] = fmaxf(acc[oc], 0.0f);
        }
    }
    __syncthreads();

    // conv3: 32ch k4 s1 -> 32ch x 19, relu  (2 oc-halves x 19 pos)
    {
        int half = tid >> 5;
        int pos  = tid & 31;
        if (pos < 19) {
            int oc0 = half * 16;
            float acc[16];
#pragma unroll
            for (int oc = 0; oc < 16; ++oc) acc[oc] = c3b[oc0 + oc];
#pragma unroll
            for (int ic = 0; ic < 32; ++ic) {
#pragma unroll
                for (int tap = 0; tap < 4; ++tap) {
                    float fv = y2[ic * 22 + pos + tap];
#pragma unroll
                    for (int oc = 0; oc < 16; ++oc)
                        acc[oc] += c3w[((oc0 + oc) * 32 + ic) * 4 + tap] * fv;
                }
            }
#pragma unroll
            for (int oc = 0; oc < 16; ++oc) y3[(oc0 + oc) * 19 + pos] = fmaxf(acc[oc], 0.0f);
        }
    }
    __syncthreads();

    // fc1: 608 -> 16, relu. lane = (u, quarter); 152 k's per lane; shfl reduce.
    {
        int u = tid & 15;
        int q = tid >> 4;          // 0..3
        float acc = 0.0f;
        int k0 = q * 152;
#pragma unroll 8
        for (int k = k0; k < k0 + 152; ++k) acc += f1w[u * 608 + k] * y3[k];
        acc += __shfl_xor(acc, 16);
        acc += __shfl_xor(acc, 32);
        if (tid < 16) r1[tid] = fmaxf(acc + f1b[tid], 0.0f);
    }
    __syncthreads();

    // fc2: 16 -> 4
    if (tid < 4) {
        float s = f2b[tid];
#pragma unroll
        for (int k = 0; k < 16; ++k) s += f2w[tid * 16 + k] * r1[k];
        out[(size_t)b * 4 + tid] = s;
    }
}

extern "C" void kernel_launch(void* const* d_in, const int* in_sizes, int n_in,
                              void* d_out, int out_size, void* d_ws, size_t ws_size,
                              hipStream_t stream)
{
    const float* x     = (const float*)d_in[0];
    const int*  lengths= (const int*)  d_in[1];
    const float* w_ih  = (const float*)d_in[2];
    const float* w_hh  = (const float*)d_in[3];
    const float* b_ih  = (const float*)d_in[4];
    const float* b_hh  = (const float*)d_in[5];
    const float* w_lin = (const float*)d_in[6];
    const float* b_lin = (const float*)d_in[7];
    const float* c1w   = (const float*)d_in[8];
    const float* c1b   = (const float*)d_in[9];
    const float* c2w   = (const float*)d_in[10];
    const float* c2b   = (const float*)d_in[11];
    const float* c3w   = (const float*)d_in[12];
    const float* c3b   = (const float*)d_in[13];
    const float* f1w   = (const float*)d_in[14];
    const float* f1b   = (const float*)d_in[15];
    const float* f2w   = (const float*)d_in[16];
    const float* f2b   = (const float*)d_in[17];
    float* out = (float*)d_out;

    // workspace layout (~15 MB total)
    char* ws      = (char*)d_ws;
    float* feat   = (float*)ws;                       // NN*16 floats
    int*   order  = (int*)(feat + (size_t)NN * NO);   // NN
    int*   len_s  = order + NN;                       // NN
    int*   hist   = len_s + NN;                       // 64
    int*   cursor = hist + 64;                        // 64
    float* bsum   = (float*)(cursor + 64);            // 80

    hipMemsetAsync(hist, 0, 64 * sizeof(int), stream);
    hist_kernel   <<<NN / 256, 256, 0, stream>>>(lengths, hist);
    scan_kernel   <<<1, 64, 0, stream>>>(hist, cursor);
    scatter_kernel<<<NN / 256, 256, 0, stream>>>(lengths, cursor, order, len_s);
    bias_kernel   <<<1, 128, 0, stream>>>(b_ih, b_hh, bsum);
    lstm_kernel   <<<NN / 64, 256, 0, stream>>>(x, len_s, order, w_ih, w_hh, bsum,
                                                w_lin, b_lin, feat);
    head_kernel   <<<NB, 64, 0, stream>>>(feat, c1w, c1b, c2w, c2b, c3w, c3b,
                                          f1w, f1b, f2w, f2b, out);
}

// Round 5
// 653.442 us; speedup vs baseline: 6.3213x; 2.2943x over previous
//
#include <hip/hip_runtime.h>
#include <cstdint>
#include <cstddef>

// Problem constants
#define NB 4096
#define NL 50
#define NT 64
#define NF 3
#define NH 20
#define NO 16
#define NN (NB*NL)    // 204800 sequences
#define SB 16         // sequences per lstm block (one wave)
#define NBLK (NN/SB)  // 12800 lstm blocks
#define TS 16         // steps per x tile
#define XTS 52        // xt stride in dwords (48 data + 4 pad, 208B)

typedef __attribute__((ext_vector_type(8))) short bf16x8;   // 8 bf16 = 4 VGPR
typedef __attribute__((ext_vector_type(4))) float f32x4;

// ---------------- fast transcendentals ----------------
__device__ __forceinline__ float fsig(float z) {
    return __builtin_amdgcn_rcpf(1.0f + __expf(-z));
}
__device__ __forceinline__ float ftanh(float z) {
    return 1.0f - 2.0f * __builtin_amdgcn_rcpf(1.0f + __expf(2.0f * z));
}
__device__ __forceinline__ unsigned short f2bf(float f) {   // RNE fp32->bf16
    unsigned int x = __float_as_uint(f);
    x = (x + 0x7fffu + ((x >> 16) & 1u)) >> 16;
    return (unsigned short)x;
}
__device__ __forceinline__ float bf2f(unsigned short u) {
    return __uint_as_float(((unsigned int)u) << 16);
}

// ---------------- counting sort by length (64 buckets) ----------------
__global__ __launch_bounds__(256) void hist_kernel(const int* __restrict__ lengths,
                                                   int* __restrict__ hist) {
    __shared__ int lh[64];
    int tid = threadIdx.x;
    if (tid < 64) lh[tid] = 0;
    __syncthreads();
    int n = blockIdx.x * 256 + tid;
    if (n < NN) {
        int len = lengths[n];
        len = len < 0 ? 0 : (len > 63 ? 63 : len);
        atomicAdd(&lh[len], 1);
    }
    __syncthreads();
    if (tid < 64 && lh[tid] != 0) atomicAdd(&hist[tid], lh[tid]);
}

__global__ void scan_kernel(const int* __restrict__ hist, int* __restrict__ cursor) {
    int l = threadIdx.x;          // 0..63
    int v = hist[l];
    int s = v;
#pragma unroll
    for (int d = 1; d < 64; d <<= 1) {
        int o = __shfl_up(s, d);
        if (l >= d) s += o;
    }
    cursor[l] = s - v;            // exclusive prefix
}

__global__ __launch_bounds__(256) void scatter_kernel(const int* __restrict__ lengths,
                                                      int* __restrict__ cursor,
                                                      int* __restrict__ order,
                                                      int* __restrict__ len_s) {
    __shared__ int lcnt[64];
    __shared__ int lbase[64];
    int tid = threadIdx.x;
    if (tid < 64) lcnt[tid] = 0;
    __syncthreads();
    int n = blockIdx.x * 256 + tid;
    int len = 0, myrank = 0;
    if (n < NN) {
        len = lengths[n];
        len = len < 0 ? 0 : (len > 63 ? 63 : len);
        myrank = atomicAdd(&lcnt[len], 1);
    }
    __syncthreads();
    if (tid < 64 && lcnt[tid] != 0) lbase[tid] = atomicAdd(&cursor[tid], lcnt[tid]);
    __syncthreads();
    if (n < NN) {
        int pos = lbase[len] + myrank;
        order[pos] = n;
        len_s[pos] = len;
    }
}

// ---------------- bias precompute: bsum = b_ih + b_hh ----------------
__global__ void bias_kernel(const float* __restrict__ b_ih,
                            const float* __restrict__ b_hh,
                            float* __restrict__ bsum) {
    int t = threadIdx.x;
    if (t < 80) bsum[t] = b_ih[t] + b_hh[t];
}

// ---------------- W fragment precompute (bf16 hi/lo A-operands) ----------------
// Tile T (gates), row m=4q+r <-> gate g = r*20 + T*4 + q. K-rows: 0..19 = w_hh,
// 20 = bsum (bias row, B supplies 1.0), 21..31 = 0. Lane l: m=l&15, kgrp=l>>4,
// element j -> k = kgrp*8+j. Terms: P=0 hi, P=1 lo (residual).
__global__ void wfrag_kernel(const float* __restrict__ w_hh,
                             const float* __restrict__ bsum,
                             unsigned int* __restrict__ wfrag) {
    int l = threadIdx.x;      // 0..63
    int m = l & 15, kg = l >> 4;
    for (int T = 0; T < 5; ++T) {
        int g = (m & 3) * 20 + T * 4 + (m >> 2);
        unsigned int hi[4], lo[4];
        for (int d = 0; d < 4; ++d) {
            unsigned int hw[2], lw[2];
            for (int e = 0; e < 2; ++e) {
                int k = kg * 8 + d * 2 + e;
                float v = 0.0f;
                if (k < 20) v = w_hh[g * 20 + k];
                else if (k == 20) v = bsum[g];
                unsigned short h16 = f2bf(v);
                float r = v - bf2f(h16);
                hw[e] = h16; lw[e] = f2bf(r);
            }
            hi[d] = hw[0] | (hw[1] << 16);
            lo[d] = lw[0] | (lw[1] << 16);
        }
        for (int d = 0; d < 4; ++d) {
            wfrag[(size_t)((T * 2 + 0) * 64 + l) * 4 + d] = hi[d];
            wfrag[(size_t)((T * 2 + 1) * 64 + l) * 4 + d] = lo[d];
        }
    }
}

// ---------------- LSTM + summary linear (MFMA recurrence) ----------------
// One wave per block, 16 seqs. Per step: Z[80x16] = (W_hi+W_lo)*[h;1] via
// 10 mfma_f32_16x16x32_bf16, + x*W_ih + activations in fp32 VALU.
// Lane (n16, kg): seq = n16, D-rows 4kg..4kg+3 = gates (i,f,g,o) of unit
// u = T*4+kg  -> c/h update fully in-register; h -> LDS bf16 for next step.
__global__ __launch_bounds__(64, 3) void lstm_kernel(
    const float* __restrict__ x,        // [NN][64][3]
    const int*   __restrict__ len_s,    // [NN] sorted lengths
    const int*   __restrict__ order,    // [NN] sorted indices
    const float* __restrict__ w_ih,     // [80][3]
    const unsigned int* __restrict__ wfrag, // [10][64][4] packed bf16 A-frags
    const float* __restrict__ w_lin,    // [16][20]
    const float* __restrict__ b_lin,    // [16]
    float* __restrict__ feat)           // [NN][16]
{
    __shared__ __align__(16) float xt[SB * XTS];            // 3328 B
    __shared__ __align__(16) unsigned short hbf[SB * 32];   // 1024 B

    const int lane = threadIdx.x;
    const int base = blockIdx.x * SB;
    const int n16  = lane & 15;
    const int kg   = lane >> 4;

    const int mylen    = len_s[base + n16];
    const int blockmax = len_s[base + SB - 1];   // ascending sort

    // init B-matrix LDS: h rows 0..19 = 0, row 20 = 1.0 (bias), 21..31 = 0
    for (int i = lane; i < SB * 32; i += 64)
        hbf[i] = ((i & 31) == 20) ? f2bf(1.0f) : (unsigned short)0;

    // W fragments: 5 tiles x {hi,lo}
    bf16x8 wf[10];
#pragma unroll
    for (int p = 0; p < 10; ++p) {
        union { uint4 i; bf16x8 v; } cv;
        cv.i = ((const uint4*)wfrag)[p * 64 + lane];
        wf[p] = cv.v;
    }

    // per-lane w_ih rows for gates g(T,r) = r*20 + T*4 + kg
    float wx[5][4][3];
#pragma unroll
    for (int T = 0; T < 5; ++T)
#pragma unroll
        for (int r = 0; r < 4; ++r) {
            int g = r * 20 + T * 4 + kg;
#pragma unroll
            for (int cc = 0; cc < 3; ++cc) wx[T][r][cc] = w_ih[g * 3 + cc];
        }

    // x gather map: 16 seqs x 12 float4 per tile = 192 = 3/lane, coalesced-ish
    size_t gb[3]; int la[3];
#pragma unroll
    for (int j = 0; j < 3; ++j) {
        int e4 = lane + 64 * j;
        int ss = e4 / 12;
        int q  = e4 - 12 * ss;
        int ns = order[base + ss];
        gb[j] = (size_t)ns * (NT * NF) + q * 4;
        la[j] = ss * XTS + q * 4;
    }

    float c5[5];
#pragma unroll
    for (int j = 0; j < 5; ++j) c5[j] = 0.0f;

    __syncthreads();

    if (blockmax > 0) {
        float4 vf[3];
#pragma unroll
        for (int j = 0; j < 3; ++j) vf[j] = *(const float4*)(x + gb[j]);

        for (int t0 = 0; t0 < blockmax; t0 += TS) {
#pragma unroll
            for (int j = 0; j < 3; ++j) *(float4*)&xt[la[j]] = vf[j];
            __syncthreads();

            if (t0 + TS < blockmax) {
                size_t off = (size_t)(t0 + TS) * NF;
#pragma unroll
                for (int j = 0; j < 3; ++j)
                    vf[j] = *(const float4*)(x + gb[j] + off);
            }

            int kmax = blockmax - t0; if (kmax > TS) kmax = TS;
            for (int k = 0; k < kmax; ++k) {
                // B fragment: [h(20); 1; 0-pad] of seq n16, k-slice kg*8..+7
                union { uint4 i; bf16x8 v; } bc;
                bc.i = *(const uint4*)&hbf[n16 * 32 + kg * 8];
                bf16x8 bfr = bc.v;

                float x0 = xt[n16 * XTS + k * 3 + 0];
                float x1 = xt[n16 * XTS + k * 3 + 1];
                float x2 = xt[n16 * XTS + k * 3 + 2];

                f32x4 acc[5];
#pragma unroll
                for (int T = 0; T < 5; ++T) {
                    f32x4 z4 = {0.f, 0.f, 0.f, 0.f};
                    z4 = __builtin_amdgcn_mfma_f32_16x16x32_bf16(wf[2*T],   bfr, z4, 0, 0, 0);
                    acc[T] = __builtin_amdgcn_mfma_f32_16x16x32_bf16(wf[2*T+1], bfr, z4, 0, 0, 0);
                }

                bool m = (t0 + k) < mylen;
#pragma unroll
                for (int T = 0; T < 5; ++T) {
                    float zi = acc[T][0] + wx[T][0][0]*x0 + wx[T][0][1]*x1 + wx[T][0][2]*x2;
                    float zf = acc[T][1] + wx[T][1][0]*x0 + wx[T][1][1]*x1 + wx[T][1][2]*x2;
                    float zg = acc[T][2] + wx[T][2][0]*x0 + wx[T][2][1]*x1 + wx[T][2][2]*x2;
                    float zo = acc[T][3] + wx[T][3][0]*x0 + wx[T][3][1]*x1 + wx[T][3][2]*x2;
                    float ig = fsig(zi), fg = fsig(zf);
                    float gg = ftanh(zg), og = fsig(zo);
                    float cn = fg * c5[T] + ig * gg;
                    float hn = og * ftanh(cn);
                    if (m) {
                        c5[T] = cn;
                        hbf[n16 * 32 + T * 4 + kg] = f2bf(hn);   // unit u = T*4+kg
                    }
                }
                __syncthreads();   // hbf writes -> next step's B-frag reads
            }
        }
    }

    // epilogue: summary linear. Thread (n16,kg) -> outputs o = 4*kg..4*kg+3
    float hl[20];
#pragma unroll
    for (int u = 0; u < 20; ++u) hl[u] = bf2f(hbf[n16 * 32 + u]);
    int n = order[base + n16];
    float4 res;
    if (mylen > 0) {
        float r4[4];
#pragma unroll
        for (int j = 0; j < 4; ++j) {
            int o = 4 * kg + j;
            float a = b_lin[o];
#pragma unroll
            for (int kk = 0; kk < 20; ++kk) a += w_lin[o * 20 + kk] * hl[kk];
            r4[j] = fsig(a);
        }
        res = make_float4(r4[0], r4[1], r4[2], r4[3]);
    } else {
        res = make_float4(0.f, 0.f, 0.f, 0.f);
    }
    *(float4*)(feat + (size_t)n * NO + 4 * kg) = res;
}

// ---------------- conv stack + fc head (one wave per batch row) ----------------
__global__ __launch_bounds__(64) void head_kernel(
    const float* __restrict__ feat,  // [NB][NL][16]
    const float* __restrict__ c1w, const float* __restrict__ c1b,
    const float* __restrict__ c2w, const float* __restrict__ c2b,
    const float* __restrict__ c3w, const float* __restrict__ c3b,
    const float* __restrict__ f1w, const float* __restrict__ f1b,
    const float* __restrict__ f2w, const float* __restrict__ f2b,
    float* __restrict__ out)         // [NB][4]
{
    const int b   = blockIdx.x;
    const int tid = threadIdx.x;

    __shared__ float sf[16 * 50];
    __shared__ float y1[32 * 46];
    __shared__ float y2[32 * 22];
    __shared__ float y3[32 * 19];
    __shared__ float r1[16];

    const float* fb = feat + (size_t)b * (NL * NO);
    for (int i = tid; i < NL * NO; i += 64) {
        int l = i >> 4, o = i & 15;
        sf[o * 50 + l] = fb[i];
    }
    __syncthreads();

    if (tid < 46) {
        float acc[32];
#pragma unroll
        for (int oc = 0; oc < 32; ++oc) acc[oc] = c1b[oc];
#pragma unroll
        for (int ic = 0; ic < 16; ++ic) {
#pragma unroll
            for (int tap = 0; tap < 5; ++tap) {
                float fv = sf[ic * 50 + tid + tap];
#pragma unroll
                for (int oc = 0; oc < 32; ++oc)
                    acc[oc] += c1w[(oc * 16 + ic) * 5 + tap] * fv;
            }
        }
#pragma unroll
        for (int oc = 0; oc < 32; ++oc) y1[oc * 46 + tid] = fmaxf(acc[oc], 0.0f);
    }
    __syncthreads();

    {
        int half = tid >> 5;
        int pos  = tid & 31;
        if (pos < 22) {
            int oc0 = half * 16;
            float acc[16];
#pragma unroll
            for (int oc = 0; oc < 16; ++oc) acc[oc] = c2b[oc0 + oc];
#pragma unroll
            for (int ic = 0; ic < 32; ++ic) {
#pragma unroll
                for (int tap = 0; tap < 4; ++tap) {
                    float fv = y1[ic * 46 + 2 * pos + tap];
#pragma unroll
                    for (int oc = 0; oc < 16; ++oc)
                        acc[oc] += c2w[((oc0 + oc) * 32 + ic) * 4 + tap] * fv;
                }
            }
#pragma unroll
            for (int oc = 0; oc < 16; ++oc) y2[(oc0 + oc) * 22 + pos] = fmaxf(acc[oc], 0.0f);
        }
    }
    __syncthreads();

    {
        int half = tid >> 5;
        int pos  = tid & 31;
        if (pos < 19) {
            int oc0 = half * 16;
            float acc[16];
#pragma unroll
            for (int oc = 0; oc < 16; ++oc) acc[oc] = c3b[oc0 + oc];
#pragma unroll
            for (int ic = 0; ic < 32; ++ic) {
#pragma unroll
                for (int tap = 0; tap < 4; ++tap) {
                    float fv = y2[ic * 22 + pos + tap];
#pragma unroll
                    for (int oc = 0; oc < 16; ++oc)
                        acc[oc] += c3w[((oc0 + oc) * 32 + ic) * 4 + tap] * fv;
                }
            }
#pragma unroll
            for (int oc = 0; oc < 16; ++oc) y3[(oc0 + oc) * 19 + pos] = fmaxf(acc[oc], 0.0f);
        }
    }
    __syncthreads();

    {
        int u = tid & 15;
        int q = tid >> 4;
        float acc = 0.0f;
        int k0 = q * 152;
#pragma unroll 8
        for (int k = k0; k < k0 + 152; ++k) acc += f1w[u * 608 + k] * y3[k];
        acc += __shfl_xor(acc, 16);
        acc += __shfl_xor(acc, 32);
        if (tid < 16) r1[tid] = fmaxf(acc + f1b[tid], 0.0f);
    }
    __syncthreads();

    if (tid < 4) {
        float s = f2b[tid];
#pragma unroll
        for (int k = 0; k < 16; ++k) s += f2w[tid * 16 + k] * r1[k];
        out[(size_t)b * 4 + tid] = s;
    }
}

extern "C" void kernel_launch(void* const* d_in, const int* in_sizes, int n_in,
                              void* d_out, int out_size, void* d_ws, size_t ws_size,
                              hipStream_t stream)
{
    const float* x     = (const float*)d_in[0];
    const int*  lengths= (const int*)  d_in[1];
    const float* w_ih  = (const float*)d_in[2];
    const float* w_hh  = (const float*)d_in[3];
    const float* b_ih  = (const float*)d_in[4];
    const float* b_hh  = (const float*)d_in[5];
    const float* w_lin = (const float*)d_in[6];
    const float* b_lin = (const float*)d_in[7];
    const float* c1w   = (const float*)d_in[8];
    const float* c1b   = (const float*)d_in[9];
    const float* c2w   = (const float*)d_in[10];
    const float* c2b   = (const float*)d_in[11];
    const float* c3w   = (const float*)d_in[12];
    const float* c3b   = (const float*)d_in[13];
    const float* f1w   = (const float*)d_in[14];
    const float* f1b   = (const float*)d_in[15];
    const float* f2w   = (const float*)d_in[16];
    const float* f2b   = (const float*)d_in[17];
    float* out = (float*)d_out;

    // workspace layout (~15 MB)
    char* ws      = (char*)d_ws;
    float* feat   = (float*)ws;                       // NN*16 floats
    int*   order  = (int*)(feat + (size_t)NN * NO);   // NN
    int*   len_s  = order + NN;                       // NN
    int*   hist   = len_s + NN;                       // 64
    int*   cursor = hist + 64;                        // 64
    float* bsum   = (float*)(cursor + 64);            // 80 (pad to 96)
    unsigned int* wfrag = (unsigned int*)(bsum + 96); // 10*64*4 = 2560

    hipMemsetAsync(hist, 0, 64 * sizeof(int), stream);
    hist_kernel   <<<NN / 256, 256, 0, stream>>>(lengths, hist);
    scan_kernel   <<<1, 64, 0, stream>>>(hist, cursor);
    scatter_kernel<<<NN / 256, 256, 0, stream>>>(lengths, cursor, order, len_s);
    bias_kernel   <<<1, 128, 0, stream>>>(b_ih, b_hh, bsum);
    wfrag_kernel  <<<1, 64, 0, stream>>>(w_hh, bsum, wfrag);
    lstm_kernel   <<<NBLK, 64, 0, stream>>>(x, len_s, order, w_ih, wfrag,
                                            w_lin, b_lin, feat);
    head_kernel   <<<NB, 64, 0, stream>>>(feat, c1w, c1b, c2w, c2b, c3w, c3b,
                                          f1w, f1b, f2w, f2b, out);
}

// Round 6
// 559.878 us; speedup vs baseline: 7.3777x; 1.1671x over previous
//
#include <hip/hip_runtime.h>
#include <cstdint>
#include <cstddef>

// Problem constants
#define NB 4096
#define NL 50
#define NT 64
#define NF 3
#define NH 20
#define NO 16
#define NN (NB*NL)    // 204800 sequences
#define SB 16         // sequences per wave
#define TS 16         // steps per x tile
#define HSTR 20       // hbf stride (shorts per seq) -> conflict-free n16*10 dw pattern
#define XSTR 8        // xbf shorts per (k,seq): {bias, xh0..2, xl0..2, 0}

typedef __attribute__((ext_vector_type(8))) short bf16x8;   // 8 bf16 = 4 VGPR
typedef __attribute__((ext_vector_type(4))) float f32x4;

// ---------------- fast transcendentals ----------------
__device__ __forceinline__ float fsig(float z) {
    return __builtin_amdgcn_rcpf(1.0f + __expf(-z));
}
__device__ __forceinline__ float ftanh(float z) {
    return 1.0f - 2.0f * __builtin_amdgcn_rcpf(1.0f + __expf(2.0f * z));
}
__device__ __forceinline__ unsigned short f2bf(float f) {   // RNE fp32->bf16
    unsigned int x = __float_as_uint(f);
    x = (x + 0x7fffu + ((x >> 16) & 1u)) >> 16;
    return (unsigned short)x;
}
__device__ __forceinline__ float bf2f(unsigned short u) {
    return __uint_as_float(((unsigned int)u) << 16);
}

// ---------------- counting sort by length (64 buckets) ----------------
__global__ __launch_bounds__(256) void hist_kernel(const int* __restrict__ lengths,
                                                   int* __restrict__ hist) {
    __shared__ int lh[64];
    int tid = threadIdx.x;
    if (tid < 64) lh[tid] = 0;
    __syncthreads();
    int n = blockIdx.x * 256 + tid;
    if (n < NN) {
        int len = lengths[n];
        len = len < 0 ? 0 : (len > 63 ? 63 : len);
        atomicAdd(&lh[len], 1);
    }
    __syncthreads();
    if (tid < 64 && lh[tid] != 0) atomicAdd(&hist[tid], lh[tid]);
}

__global__ void scan_kernel(const int* __restrict__ hist, int* __restrict__ cursor) {
    int l = threadIdx.x;          // 0..63
    int v = hist[l];
    int s = v;
#pragma unroll
    for (int d = 1; d < 64; d <<= 1) {
        int o = __shfl_up(s, d);
        if (l >= d) s += o;
    }
    cursor[l] = s - v;            // exclusive prefix
}

__global__ __launch_bounds__(256) void scatter_kernel(const int* __restrict__ lengths,
                                                      int* __restrict__ cursor,
                                                      int* __restrict__ order,
                                                      int* __restrict__ len_s) {
    __shared__ int lcnt[64];
    __shared__ int lbase[64];
    int tid = threadIdx.x;
    if (tid < 64) lcnt[tid] = 0;
    __syncthreads();
    int n = blockIdx.x * 256 + tid;
    int len = 0, myrank = 0;
    if (n < NN) {
        len = lengths[n];
        len = len < 0 ? 0 : (len > 63 ? 63 : len);
        myrank = atomicAdd(&lcnt[len], 1);
    }
    __syncthreads();
    if (tid < 64 && lcnt[tid] != 0) lbase[tid] = atomicAdd(&cursor[tid], lcnt[tid]);
    __syncthreads();
    if (n < NN) {
        int pos = lbase[len] + myrank;
        order[pos] = n;
        len_s[pos] = len;
    }
}

// ---------------- bias precompute: bsum = b_ih + b_hh ----------------
__global__ void bias_kernel(const float* __restrict__ b_ih,
                            const float* __restrict__ b_hh,
                            float* __restrict__ bsum) {
    int t = threadIdx.x;
    if (t < 80) bsum[t] = b_ih[t] + b_hh[t];
}

// ---------------- W fragment precompute (bf16 hi/lo A-operands) ----------------
// K rows: 0..19 w_hh, 20 bsum (B row=1.0), 21..23 w_ih (B=x_hi),
// 24..26 w_ih again (B=x_lo), 27..31 zero. Row m <-> gate g=(m&3)*20+T*4+(m>>2).
__global__ void wfrag_kernel(const float* __restrict__ w_hh,
                             const float* __restrict__ bsum,
                             const float* __restrict__ w_ih,
                             unsigned int* __restrict__ wfrag) {
    int l = threadIdx.x;      // 0..63
    int m = l & 15, kg = l >> 4;
    for (int T = 0; T < 5; ++T) {
        int g = (m & 3) * 20 + T * 4 + (m >> 2);
        unsigned int hi[4], lo[4];
        for (int d = 0; d < 4; ++d) {
            unsigned int hw[2], lw[2];
            for (int e = 0; e < 2; ++e) {
                int k = kg * 8 + d * 2 + e;
                float v = 0.0f;
                if (k < 20)       v = w_hh[g * 20 + k];
                else if (k == 20) v = bsum[g];
                else if (k <= 23) v = w_ih[g * 3 + (k - 21)];
                else if (k <= 26) v = w_ih[g * 3 + (k - 24)];
                unsigned short h16 = f2bf(v);
                float r = v - bf2f(h16);
                hw[e] = h16; lw[e] = f2bf(r);
            }
            hi[d] = hw[0] | (hw[1] << 16);
            lo[d] = lw[0] | (lw[1] << 16);
        }
        for (int d = 0; d < 4; ++d) {
            wfrag[(size_t)((T * 2 + 0) * 64 + l) * 4 + d] = hi[d];
            wfrag[(size_t)((T * 2 + 1) * 64 + l) * 4 + d] = lo[d];
        }
    }
}

// ---------------- LSTM + summary linear (MFMA, 4 independent waves/block) ----
// Wave-private LDS slices; NO barriers in the step loop (same-wave LDS
// ordering via compiler lgkmcnt). B-frag = 2x ds_read_b64 assembling
// [h | bias,x_hi | x_lo,0]; x/bias fully inside the MFMA.
__global__ __launch_bounds__(256) void lstm_kernel(
    const float* __restrict__ x,        // [NN][64][3]
    const int*   __restrict__ len_s,    // [NN] sorted lengths
    const int*   __restrict__ order,    // [NN] sorted indices
    const unsigned int* __restrict__ wfrag, // [10][64][4]
    const float* __restrict__ w_lin,    // [16][20]
    const float* __restrict__ b_lin,    // [16]
    float* __restrict__ feat)           // [NN][16]
{
    __shared__ __align__(16) unsigned short hbf[4][SB * HSTR];       // 2.5 KB
    __shared__ __align__(16) unsigned short xbf[4][TS * SB * XSTR];  // 16 KB
    __shared__ __align__(16) unsigned short zbuf[4][8];              // 64 B

    const int tid  = threadIdx.x;
    const int wid  = __builtin_amdgcn_readfirstlane(tid >> 6);
    const int lane = tid & 63;
    const int n16  = lane & 15;
    const int kg   = lane >> 4;
    const int base = (blockIdx.x * 4 + wid) * SB;

    const int mylen   = len_s[base + n16];
    const int wavemax = len_s[base + SB - 1];    // ascending sort

    // per-wave LDS init (no cross-wave deps -> no barrier)
    for (int i = lane; i < SB * HSTR; i += 64) hbf[wid][i] = 0;
    if (lane < 8) zbuf[wid][lane] = 0;
    for (int i = lane; i < TS * SB; i += 64) {
        xbf[wid][i * XSTR + 0] = 0x3F80;   // bias row = 1.0
        xbf[wid][i * XSTR + 7] = 0;        // K row 27 pad = 0
    }

    // W fragments: 5 tiles x {hi,lo}
    bf16x8 wf[10];
#pragma unroll
    for (int p = 0; p < 10; ++p) {
        union { uint4 i; bf16x8 v; } cv;
        cv.i = ((const uint4*)wfrag)[p * 64 + lane];
        wf[p] = cv.v;
    }

    // x gather map: 16 seqs x 12 float4 = 192 per tile = 3/lane
    int nown = order[base + n16];
    size_t gb[3]; int ssj[3], qqj[3];
#pragma unroll
    for (int j = 0; j < 3; ++j) {
        int e4 = lane + 64 * j;
        int ss = e4 / 12;
        int q  = e4 - 12 * ss;
        int ns = __shfl(nown, ss);
        gb[j] = (size_t)ns * (NT * NF) + q * 4;
        ssj[j] = ss; qqj[j] = q;
    }

    // step-loop LDS addressing: frag = [p1: rows 8kg..8kg+3][p2: rows +4..+7]
    const unsigned short* hpw = &hbf[wid][n16 * HSTR];
    const unsigned short* p1 = (kg < 3) ? (hpw + kg * 8)
                                        : &xbf[wid][n16 * XSTR + 4];
    const unsigned short* p2 = (kg < 2) ? (hpw + kg * 8 + 4)
                             : (kg == 2 ? &xbf[wid][n16 * XSTR]
                                        : &zbuf[wid][0]);
    const int st1 = (kg == 3) ? SB * XSTR : 0;   // shorts per step
    const int st2 = (kg == 2) ? SB * XSTR : 0;

    float c5[5];
#pragma unroll
    for (int j = 0; j < 5; ++j) c5[j] = 0.0f;

    if (wavemax > 0) {
        float4 vf[3];
#pragma unroll
        for (int j = 0; j < 3; ++j) vf[j] = *(const float4*)(x + gb[j]);

        for (int t0 = 0; t0 < wavemax; t0 += TS) {
            // stage tile: fp32 regs -> bf16 hi/lo in xbf
#pragma unroll
            for (int j = 0; j < 3; ++j) {
                float fv4[4] = {vf[j].x, vf[j].y, vf[j].z, vf[j].w};
                int ss = ssj[j], q = qqj[j];
#pragma unroll
                for (int e = 0; e < 4; ++e) {
                    int fi = q * 4 + e;
                    int t  = fi / 3;
                    int cc = fi - 3 * t;
                    unsigned short hi = f2bf(fv4[e]);
                    unsigned short lo = f2bf(fv4[e] - bf2f(hi));
                    int bidx = (t * SB + ss) * XSTR;
                    xbf[wid][bidx + 1 + cc] = hi;
                    xbf[wid][bidx + 4 + cc] = lo;
                }
            }
            // prefetch next tile
            if (t0 + TS < wavemax) {
                size_t off = (size_t)(t0 + TS) * NF;
#pragma unroll
                for (int j = 0; j < 3; ++j)
                    vf[j] = *(const float4*)(x + gb[j] + off);
            }

            int kmax = wavemax - t0; if (kmax > TS) kmax = TS;
            for (int k = 0; k < kmax; ++k) {
                uint2 a = *(const uint2*)(p1 + k * st1);
                uint2 b = *(const uint2*)(p2 + k * st2);
                union { uint4 u; bf16x8 v; } bb;
                bb.u = make_uint4(a.x, a.y, b.x, b.y);

                f32x4 acc[5];
#pragma unroll
                for (int T = 0; T < 5; ++T) {
                    f32x4 z4 = {0.f, 0.f, 0.f, 0.f};
                    z4 = __builtin_amdgcn_mfma_f32_16x16x32_bf16(wf[2*T],   bb.v, z4, 0, 0, 0);
                    acc[T] = __builtin_amdgcn_mfma_f32_16x16x32_bf16(wf[2*T+1], bb.v, z4, 0, 0, 0);
                }

                bool m = (t0 + k) < mylen;
#pragma unroll
                for (int T = 0; T < 5; ++T) {
                    float ig = fsig(acc[T][0]);
                    float fg = fsig(acc[T][1]);
                    float gg = ftanh(acc[T][2]);
                    float og = fsig(acc[T][3]);
                    float cn = fg * c5[T] + ig * gg;
                    float hn = og * ftanh(cn);
                    if (m) {
                        c5[T] = cn;
                        hbf[wid][n16 * HSTR + T * 4 + kg] = f2bf(hn);
                    }
                }
            }
        }
    }

    // epilogue: summary linear. Lane (n16,kg) -> outputs o = 4*kg..4*kg+3
    float hl[NH];
#pragma unroll
    for (int u = 0; u < NH; ++u) hl[u] = bf2f(hbf[wid][n16 * HSTR + u]);
    float4 res;
    if (mylen > 0) {
        float r4[4];
#pragma unroll
        for (int j = 0; j < 4; ++j) {
            int o = 4 * kg + j;
            float aa = b_lin[o];
#pragma unroll
            for (int kk = 0; kk < NH; ++kk) aa += w_lin[o * NH + kk] * hl[kk];
            r4[j] = fsig(aa);
        }
        res = make_float4(r4[0], r4[1], r4[2], r4[3]);
    } else {
        res = make_float4(0.f, 0.f, 0.f, 0.f);
    }
    *(float4*)(feat + (size_t)nown * NO + 4 * kg) = res;
}

// ---------------- conv stack + fc head: 256 thr = 4 waves per batch row ----
// Wave q handles output channels q*8..q*8+7 (wave-uniform weight indices ->
// s_load path); positions on lanes. LDS shared per block -> ~32 waves/CU.
__global__ __launch_bounds__(256) void head_kernel(
    const float* __restrict__ feat,  // [NB][NL][16]
    const float* __restrict__ c1w, const float* __restrict__ c1b,
    const float* __restrict__ c2w, const float* __restrict__ c2b,
    const float* __restrict__ c3w, const float* __restrict__ c3b,
    const float* __restrict__ f1w, const float* __restrict__ f1b,
    const float* __restrict__ f2w, const float* __restrict__ f2b,
    float* __restrict__ out)         // [NB][4]
{
    const int b   = blockIdx.x;
    const int tid = threadIdx.x;
    const int p   = tid & 63;
    const int q   = __builtin_amdgcn_readfirstlane(tid >> 6);  // oc-octet 0..3

    __shared__ float sf[16 * 50];   // 3.2 KB
    __shared__ float y1[32 * 46];   // 5.9 KB
    __shared__ float y2[32 * 22];   // 2.8 KB
    __shared__ float y3[32 * 19];   // 2.4 KB
    __shared__ float r1[16];

    const float* fb = feat + (size_t)b * (NL * NO);
    for (int i = tid; i < NL * NO; i += 256) {
        int l = i >> 4, o = i & 15;
        sf[o * 50 + l] = fb[i];
    }
    __syncthreads();

    // conv1: 16ch k5 s1 -> 32ch x 46, relu. lane p = position, wave q = 8 oc
    if (p < 46) {
        int oc0 = q * 8;
        float acc[8];
#pragma unroll
        for (int oc = 0; oc < 8; ++oc) acc[oc] = c1b[oc0 + oc];
#pragma unroll
        for (int ic = 0; ic < 16; ++ic) {
#pragma unroll
            for (int tap = 0; tap < 5; ++tap) {
                float fv = sf[ic * 50 + p + tap];
#pragma unroll
                for (int oc = 0; oc < 8; ++oc)
                    acc[oc] += c1w[((oc0 + oc) * 16 + ic) * 5 + tap] * fv;
            }
        }
#pragma unroll
        for (int oc = 0; oc < 8; ++oc) y1[(oc0 + oc) * 46 + p] = fmaxf(acc[oc], 0.0f);
    }
    __syncthreads();

    // conv2: 32ch k4 s2 -> 32ch x 22, relu
    if (p < 22) {
        int oc0 = q * 8;
        float acc[8];
#pragma unroll
        for (int oc = 0; oc < 8; ++oc) acc[oc] = c2b[oc0 + oc];
#pragma unroll
        for (int ic = 0; ic < 32; ++ic) {
#pragma unroll
            for (int tap = 0; tap < 4; ++tap) {
                float fv = y1[ic * 46 + 2 * p + tap];
#pragma unroll
                for (int oc = 0; oc < 8; ++oc)
                    acc[oc] += c2w[((oc0 + oc) * 32 + ic) * 4 + tap] * fv;
            }
        }
#pragma unroll
        for (int oc = 0; oc < 8; ++oc) y2[(oc0 + oc) * 22 + p] = fmaxf(acc[oc], 0.0f);
    }
    __syncthreads();

    // conv3: 32ch k4 s1 -> 32ch x 19, relu
    if (p < 19) {
        int oc0 = q * 8;
        float acc[8];
#pragma unroll
        for (int oc = 0; oc < 8; ++oc) acc[oc] = c3b[oc0 + oc];
#pragma unroll
        for (int ic = 0; ic < 32; ++ic) {
#pragma unroll
            for (int tap = 0; tap < 4; ++tap) {
                float fv = y2[ic * 22 + p + tap];
#pragma unroll
                for (int oc = 0; oc < 8; ++oc)
                    acc[oc] += c3w[((oc0 + oc) * 32 + ic) * 4 + tap] * fv;
            }
        }
#pragma unroll
        for (int oc = 0; oc < 8; ++oc) y3[(oc0 + oc) * 19 + p] = fmaxf(acc[oc], 0.0f);
    }
    __syncthreads();

    // fc1: 608 -> 16, relu (wave 0 only). lane=(u, quarter), shfl reduce.
    if (tid < 64) {
        int u  = tid & 15;
        int qq = tid >> 4;
        float acc = 0.0f;
        int k0 = qq * 152;
#pragma unroll 8
        for (int k = k0; k < k0 + 152; ++k) acc += f1w[u * 608 + k] * y3[k];
        acc += __shfl_xor(acc, 16);
        acc += __shfl_xor(acc, 32);
        if (tid < 16) r1[tid] = fmaxf(acc + f1b[tid], 0.0f);
    }
    __syncthreads();

    // fc2: 16 -> 4
    if (tid < 4) {
        float s = f2b[tid];
#pragma unroll
        for (int k = 0; k < 16; ++k) s += f2w[tid * 16 + k] * r1[k];
        out[(size_t)b * 4 + tid] = s;
    }
}

extern "C" void kernel_launch(void* const* d_in, const int* in_sizes, int n_in,
                              void* d_out, int out_size, void* d_ws, size_t ws_size,
                              hipStream_t stream)
{
    const float* x     = (const float*)d_in[0];
    const int*  lengths= (const int*)  d_in[1];
    const float* w_ih  = (const float*)d_in[2];
    const float* w_hh  = (const float*)d_in[3];
    const float* b_ih  = (const float*)d_in[4];
    const float* b_hh  = (const float*)d_in[5];
    const float* w_lin = (const float*)d_in[6];
    const float* b_lin = (const float*)d_in[7];
    const float* c1w   = (const float*)d_in[8];
    const float* c1b   = (const float*)d_in[9];
    const float* c2w   = (const float*)d_in[10];
    const float* c2b   = (const float*)d_in[11];
    const float* c3w   = (const float*)d_in[12];
    const float* c3b   = (const float*)d_in[13];
    const float* f1w   = (const float*)d_in[14];
    const float* f1b   = (const float*)d_in[15];
    const float* f2w   = (const float*)d_in[16];
    const float* f2b   = (const float*)d_in[17];
    float* out = (float*)d_out;

    // workspace layout (~15 MB)
    char* ws      = (char*)d_ws;
    float* feat   = (float*)ws;                       // NN*16 floats
    int*   order  = (int*)(feat + (size_t)NN * NO);   // NN
    int*   len_s  = order + NN;                       // NN
    int*   hist   = len_s + NN;                       // 64
    int*   cursor = hist + 64;                        // 64
    float* bsum   = (float*)(cursor + 64);            // 80 (pad 96)
    unsigned int* wfrag = (unsigned int*)(bsum + 96); // 2560

    hipMemsetAsync(hist, 0, 64 * sizeof(int), stream);
    hist_kernel   <<<NN / 256, 256, 0, stream>>>(lengths, hist);
    scan_kernel   <<<1, 64, 0, stream>>>(hist, cursor);
    scatter_kernel<<<NN / 256, 256, 0, stream>>>(lengths, cursor, order, len_s);
    bias_kernel   <<<1, 128, 0, stream>>>(b_ih, b_hh, bsum);
    wfrag_kernel  <<<1, 64, 0, stream>>>(w_hh, bsum, w_ih, wfrag);
    lstm_kernel   <<<NN / (SB * 4), 256, 0, stream>>>(x, len_s, order, wfrag,
                                                      w_lin, b_lin, feat);
    head_kernel   <<<NB, 256, 0, stream>>>(feat, c1w, c1b, c2w, c2b, c3w, c3b,
                                           f1w, f1b, f2w, f2b, out);
}